// Round 2
// baseline (455.417 us; speedup 1.0000x reference)
//
#include <hip/hip_runtime.h>
#include <stdint.h>

#define NPOLAR 1024
#define KT 512
#define BLOCK 256
#define PITCH 33   // xl pitch: 32 words + 1 pad
#define PKP 18     // packed-row pitch (words): 8B-aligned b64 reads, ~4-way (cheap) conflicts
#define ROWS2 16   // rows per block in expand kernel

__device__ __forceinline__ uint32_t fbit(float f) {
    return (__float_as_uint(f) >> 29) & 1u;   // exact 0.0f/1.0f inputs
}

// ---------------- Kernel 1: pack + CRC + scatter + butterfly -> packed words ----------------
__global__ __launch_bounds__(BLOCK) void polar_pack_kernel(
    const float* __restrict__ u,
    const float* __restrict__ crc_gen,
    const int* __restrict__ info_pos,
    uint32_t* __restrict__ pko)               // [rows][32]
{
    __shared__ uint32_t pk[BLOCK * PKP];
    __shared__ uint32_t xl[BLOCK * PITCH];
    __shared__ uint32_t gc[11 * 16];
    __shared__ int ip[544];

    const int t   = threadIdx.x;
    const int blk = blockIdx.x;

    // info_pos -> LDS
    for (int i = t; i < 523; i += BLOCK) ip[i] = info_pos[i];

    // packed CRC generator columns
    if (t < 176) {
        int j = t / 16, w = t % 16;
        uint32_t g = 0;
        #pragma unroll
        for (int i = 0; i < 32; ++i)
            g |= fbit(crc_gen[(32 * w + i) * 11 + j]) << i;
        gc[j * 16 + w] = g;
    }

    // ---- Phase A: cooperative coalesced pack ----
    // flat float4 index f = t + 256*i over the block's 256x512 tile.
    // row = f>>7 = (t>>7) + 2i ; word = (f>>3)&15 = (t>>3)&15 (const) ; slot = f&7 = t&7 (const)
    {
        const int slot = t & 7;
        const int w0   = (t >> 3) & 15;
        const int rpar = t >> 7;
        const float4* uv = reinterpret_cast<const float4*>(u) + (size_t)blk * (BLOCK * KT / 4) + t;
        #pragma unroll 4
        for (int i = 0; i < 128; ++i) {
            float4 f = uv[(size_t)i * 256];
            uint32_t nib = fbit(f.x) | (fbit(f.y) << 1) | (fbit(f.z) << 2) | (fbit(f.w) << 3);
            uint32_t val = nib << (slot * 4);
            val |= __shfl_xor(val, 1);
            val |= __shfl_xor(val, 2);
            val |= __shfl_xor(val, 4);
            if (slot == 0) pk[(rpar + 2 * i) * PKP + w0] = val;
        }
    }
    __syncthreads();

    // ---- Phase B: load my packed row + CRC-11 ----
    uint32_t uw[16];
    #pragma unroll
    for (int j = 0; j < 8; ++j) {
        uint2 v = *reinterpret_cast<uint2*>(&pk[t * PKP + 2 * j]);
        uw[2 * j] = v.x; uw[2 * j + 1] = v.y;
    }
    uint32_t parity = 0;
    #pragma unroll
    for (int j = 0; j < 11; ++j) {
        uint32_t acc = 0;
        #pragma unroll
        for (int w = 0; w < 16; ++w) acc ^= uw[w] & gc[j * 16 + w];
        parity |= (uint32_t)(__popc(acc) & 1) << j;
    }

    // ---- Phase C: scatter 523 info bits into frame (run-flush, dst sorted) ----
    #pragma unroll
    for (int w = 0; w < 32; ++w) xl[t * PITCH + w] = 0;
    {
        int cw = -1; uint32_t cur = 0;
        #pragma unroll
        for (int sw = 0; sw < 17; ++sw) {
            uint32_t src = (sw < 16) ? uw[sw] : parity;
            const int nb = (sw < 16) ? 32 : 11;
            #pragma unroll 8
            for (int b = 0; b < nb; ++b) {
                int pos = ip[sw * 32 + b];
                int w = pos >> 5;
                if (w != cw) {
                    if (cw >= 0) xl[t * PITCH + cw] = cur;
                    cur = 0; cw = w;
                }
                cur |= ((src >> b) & 1u) << (pos & 31);
            }
        }
        xl[t * PITCH + cw] = cur;
    }

    // ---- Phase D: 10-stage butterfly in registers ----
    uint32_t x[32];
    #pragma unroll
    for (int w = 0; w < 32; ++w) x[w] = xl[t * PITCH + w];
    #pragma unroll
    for (int w = 0; w < 32; ++w) {
        uint32_t v = x[w];
        v ^= (v >> 1)  & 0x55555555u;
        v ^= (v >> 2)  & 0x33333333u;
        v ^= (v >> 4)  & 0x0F0F0F0Fu;
        v ^= (v >> 8)  & 0x00FF00FFu;
        v ^= (v >> 16) & 0x0000FFFFu;
        x[w] = v;
    }
    #pragma unroll
    for (int d = 1; d <= 16; d <<= 1) {
        #pragma unroll
        for (int w = 0; w < 32; ++w)
            if ((w & d) == 0) x[w] ^= x[w + d];
    }
    #pragma unroll
    for (int w = 0; w < 32; ++w) xl[t * PITCH + w] = x[w];
    __syncthreads();

    // ---- Phase E': cooperative coalesced store of packed rows ----
    uint32_t* dst = pko + (size_t)blk * (BLOCK * 32);
    #pragma unroll
    for (int i = 0; i < 32; ++i) {
        int f = i * BLOCK + t;
        dst[f] = xl[(f >> 5) * PITCH + (f & 31)];
    }
}

// ---------------- Kernel 2: permuted expansion to floats (high occupancy) ----------------
__global__ __launch_bounds__(BLOCK) void polar_expand_kernel(
    const uint32_t* __restrict__ pki,
    const int* __restrict__ perm_out,
    float* __restrict__ out)
{
    __shared__ uint32_t xl[ROWS2 * PITCH];
    const int t   = threadIdx.x;
    const int blk = blockIdx.x;

    if (t < ROWS2 * 32 / 4) {
        uint4 v = reinterpret_cast<const uint4*>(pki + (size_t)blk * (ROWS2 * 32))[t];
        int w4 = t * 4, row = w4 >> 5, w = w4 & 31;
        xl[row * PITCH + w]     = v.x;
        xl[row * PITCH + w + 1] = v.y;
        xl[row * PITCH + w + 2] = v.z;
        xl[row * PITCH + w + 3] = v.w;
    }
    const int4 pv = reinterpret_cast<const int4*>(perm_out)[t];
    const int a0 = pv.x >> 5, s0 = pv.x & 31;
    const int a1 = pv.y >> 5, s1 = pv.y & 31;
    const int a2 = pv.z >> 5, s2 = pv.z & 31;
    const int a3 = pv.w >> 5, s3 = pv.w & 31;
    __syncthreads();

    float4* outv = reinterpret_cast<float4*>(out) + (size_t)blk * (ROWS2 * (NPOLAR / 4)) + t;
    #pragma unroll
    for (int k = 0; k < ROWS2; ++k) {
        const uint32_t* rowp = &xl[k * PITCH];
        float4 o;
        o.x = (float)((rowp[a0] >> s0) & 1u);
        o.y = (float)((rowp[a1] >> s1) & 1u);
        o.z = (float)((rowp[a2] >> s2) & 1u);
        o.w = (float)((rowp[a3] >> s3) & 1u);
        outv[(size_t)k * (NPOLAR / 4)] = o;
    }
}

// ---------------- Fallback: previous fused single kernel (used only if ws too small) ------
__global__ __launch_bounds__(BLOCK) void polar_enc_fused(
    const float* __restrict__ u,
    const float* __restrict__ crc_gen,
    const int* __restrict__ info_pos,
    const int* __restrict__ perm_out,
    float* __restrict__ out)
{
    __shared__ uint32_t xl[BLOCK * PITCH];
    __shared__ uint32_t gc[11 * 16];
    const int t = threadIdx.x, blk = blockIdx.x, row = blk * BLOCK + t;
    if (t < 176) {
        int j = t / 16, w = t % 16;
        uint32_t g = 0;
        #pragma unroll
        for (int i = 0; i < 32; ++i)
            g |= fbit(crc_gen[(32 * w + i) * 11 + j]) << i;
        gc[j * 16 + w] = g;
    }
    uint32_t uw[16];
    const float4* uv = reinterpret_cast<const float4*>(u + (size_t)row * KT);
    #pragma unroll
    for (int w = 0; w < 16; ++w) {
        uint32_t acc = 0;
        #pragma unroll
        for (int q = 0; q < 8; ++q) {
            float4 f = uv[w * 8 + q];
            acc |= fbit(f.x) << (4 * q) | fbit(f.y) << (4 * q + 1)
                 | fbit(f.z) << (4 * q + 2) | fbit(f.w) << (4 * q + 3);
        }
        uw[w] = acc;
    }
    __syncthreads();
    uint32_t parity = 0;
    #pragma unroll
    for (int j = 0; j < 11; ++j) {
        uint32_t acc = 0;
        #pragma unroll
        for (int w = 0; w < 16; ++w) acc ^= uw[w] & gc[j * 16 + w];
        parity |= (uint32_t)(__popc(acc) & 1) << j;
    }
    #pragma unroll
    for (int w = 0; w < 32; ++w) xl[t * PITCH + w] = 0;
    {
        int cw = -1; uint32_t cur = 0;
        #pragma unroll
        for (int sw = 0; sw < 17; ++sw) {
            uint32_t src = (sw < 16) ? uw[sw] : parity;
            const int nb = (sw < 16) ? 32 : 11;
            for (int b = 0; b < nb; ++b) {
                int pos = info_pos[sw * 32 + b];
                int w = pos >> 5;
                if (w != cw) { if (cw >= 0) xl[t * PITCH + cw] = cur; cur = 0; cw = w; }
                cur |= ((src >> b) & 1u) << (pos & 31);
            }
        }
        xl[t * PITCH + cw] = cur;
    }
    uint32_t x[32];
    #pragma unroll
    for (int w = 0; w < 32; ++w) x[w] = xl[t * PITCH + w];
    #pragma unroll
    for (int w = 0; w < 32; ++w) {
        uint32_t v = x[w];
        v ^= (v >> 1) & 0x55555555u; v ^= (v >> 2) & 0x33333333u;
        v ^= (v >> 4) & 0x0F0F0F0Fu; v ^= (v >> 8) & 0x00FF00FFu;
        v ^= (v >> 16) & 0x0000FFFFu;
        x[w] = v;
    }
    #pragma unroll
    for (int d = 1; d <= 16; d <<= 1)
        #pragma unroll
        for (int w = 0; w < 32; ++w)
            if ((w & d) == 0) x[w] ^= x[w + d];
    #pragma unroll
    for (int w = 0; w < 32; ++w) xl[t * PITCH + w] = x[w];
    __syncthreads();
    const int4 pv = reinterpret_cast<const int4*>(perm_out)[t];
    const int a0 = pv.x >> 5, s0 = pv.x & 31;
    const int a1 = pv.y >> 5, s1 = pv.y & 31;
    const int a2 = pv.z >> 5, s2 = pv.z & 31;
    const int a3 = pv.w >> 5, s3 = pv.w & 31;
    float4* outv = reinterpret_cast<float4*>(out) + (size_t)blk * BLOCK * (NPOLAR / 4) + t;
    #pragma unroll 4
    for (int k = 0; k < BLOCK; ++k) {
        const uint32_t* rowp = &xl[k * PITCH];
        float4 o;
        o.x = (float)((rowp[a0] >> s0) & 1u);
        o.y = (float)((rowp[a1] >> s1) & 1u);
        o.z = (float)((rowp[a2] >> s2) & 1u);
        o.w = (float)((rowp[a3] >> s3) & 1u);
        outv[(size_t)k * (NPOLAR / 4)] = o;
    }
}

extern "C" void kernel_launch(void* const* d_in, const int* in_sizes, int n_in,
                              void* d_out, int out_size, void* d_ws, size_t ws_size,
                              hipStream_t stream) {
    const float* u        = (const float*)d_in[0];
    const float* crc_gen  = (const float*)d_in[1];
    const int*   info_pos = (const int*)d_in[2];
    const int*   perm_out = (const int*)d_in[4];
    float* out = (float*)d_out;

    const int rows  = in_sizes[0] / KT;            // 65536
    const size_t need = (size_t)rows * 32 * sizeof(uint32_t);  // 8 MB packed

    if (ws_size >= need) {
        uint32_t* pk = (uint32_t*)d_ws;
        polar_pack_kernel<<<rows / BLOCK, BLOCK, 0, stream>>>(u, crc_gen, info_pos, pk);
        polar_expand_kernel<<<rows / ROWS2, BLOCK, 0, stream>>>(pk, perm_out, out);
    } else {
        polar_enc_fused<<<rows / BLOCK, BLOCK, 0, stream>>>(u, crc_gen, info_pos, perm_out, out);
    }
}

// Round 3
// 383.583 us; speedup vs baseline: 1.1873x; 1.1873x over previous
//
#include <hip/hip_runtime.h>
#include <stdint.h>

#define NPOLAR 1024
#define KT 512
#define BLOCK 256
#define ROWS 32            // rows per block
#define PKP 18             // packed source row pitch: 16 words + parity + zero pad
#define XLP 36             // encoded row pitch: 32 words + pad (16B-aligned uint4 slots)

__device__ __forceinline__ uint32_t fbit(float f) {
    return (__float_as_uint(f) >> 29) & 1u;   // inputs are exactly 0.0f / 1.0f
}

__global__ __launch_bounds__(BLOCK, 8) void polar_all_kernel(
    const float* __restrict__ u,
    const float* __restrict__ crc_gen,
    const int* __restrict__ info_pos,
    const int* __restrict__ perm_out,
    float* __restrict__ out)
{
    __shared__ uint32_t pk[ROWS * PKP];   // packed info stream per row (+parity,+0)
    __shared__ uint32_t xl[ROWS * XLP];   // encoded rows
    __shared__ uint32_t gc[11 * 16];      // packed CRC generator columns
    __shared__ uint32_t mw[32];           // info-bit mask per dest word
    __shared__ uint32_t cw[32];           // stream rank (bits before word w)

    const int t   = threadIdx.x;
    const int blk = blockIdx.x;
    const int r   = t >> 3;               // row within block (0..31)
    const int q   = t & 7;                // part within row (0..7), lane-local

    if (t < 32) mw[t] = 0;
    __syncthreads();

    // ---- per-block tables (uniform, L2-hot) ----
    for (int i = t; i < 523; i += BLOCK) {
        int pos = info_pos[i];
        atomicOr(&mw[pos >> 5], 1u << (pos & 31));
    }
    if (t < 176) {
        int j = t / 16, w = t % 16;
        uint32_t g = 0;
        #pragma unroll
        for (int i = 0; i < 32; ++i)
            g |= fbit(crc_gen[(32 * w + i) * 11 + j]) << i;
        gc[j * 16 + w] = g;
    }

    // ---- Phase A: coalesced pack 32x512 floats -> pk (shfl nibble-combine) ----
    {
        const int slot = t & 7;
        const int w0   = (t >> 3) & 15;
        const int rpar = t >> 7;          // 0 or 1
        const float4* uv = reinterpret_cast<const float4*>(u) + (size_t)blk * (ROWS * KT / 4) + t;
        #pragma unroll
        for (int i = 0; i < 16; ++i) {
            float4 f = uv[(size_t)i * 256];
            uint32_t nib = fbit(f.x) | (fbit(f.y) << 1) | (fbit(f.z) << 2) | (fbit(f.w) << 3);
            uint32_t val = nib << (slot * 4);
            val |= __shfl_xor(val, 1);
            val |= __shfl_xor(val, 2);
            val |= __shfl_xor(val, 4);
            if (slot == 0) pk[(rpar + 2 * i) * PKP + w0] = val;
        }
    }
    __syncthreads();   // pk, mw, gc ready

    // ---- ranks: cw[w] = # info bits before word w ----
    if (t < 32) {
        uint32_t c = 0;
        for (int v = 0; v < t; ++v) c += __popc(mw[v]);
        cw[t] = c;
    }

    // ---- Phase B: CRC-11, 8-way split per row ----
    {
        uint32_t a = pk[r * PKP + 2 * q], b = pk[r * PKP + 2 * q + 1];
        uint32_t par = 0;
        #pragma unroll
        for (int j = 0; j < 11; ++j) {
            uint32_t acc = (a & gc[j * 16 + 2 * q]) ^ (b & gc[j * 16 + 2 * q + 1]);
            par |= (uint32_t)(__popc(acc) & 1) << j;
        }
        par ^= __shfl_xor(par, 1);
        par ^= __shfl_xor(par, 2);
        par ^= __shfl_xor(par, 4);
        if (q == 0) pk[r * PKP + 16] = par;   // stream word 16 = parity
        if (q == 1) pk[r * PKP + 17] = 0;     // stream word 17 = zero pad
    }
    __syncthreads();   // cw + parity ready

    // ---- Phase C: scatter via mask/rank (4 dest words per thread) ----
    uint32_t xr[4];
    {
        const uint32_t* row = &pk[r * PKP];
        #pragma unroll
        for (int j = 0; j < 4; ++j) {
            int w = 4 * q + j;
            uint32_t m = mw[w];
            uint32_t c = cw[w];
            int k = c >> 5, sh = c & 31;
            uint64_t win = (((uint64_t)row[k + 1] << 32) | row[k]) >> sh;
            uint32_t x;
            if (m == 0xFFFFFFFFu) {
                x = (uint32_t)win;            // fully-info word: straight extract
            } else {
                x = 0;
                uint32_t wv = (uint32_t)win;  // need at most popc(m) <= 32 bits
                while (m) {
                    int b = __builtin_ctz(m);
                    m &= m - 1;
                    x |= (wv & 1u) << b;
                    wv >>= 1;
                }
            }
            xr[j] = x;
        }
    }

    // ---- Phase D: butterfly. In-word stages (d=1..16 bits) ----
    #pragma unroll
    for (int j = 0; j < 4; ++j) {
        uint32_t v = xr[j];
        v ^= (v >> 1)  & 0x55555555u;
        v ^= (v >> 2)  & 0x33333333u;
        v ^= (v >> 4)  & 0x0F0F0F0Fu;
        v ^= (v >> 8)  & 0x00FF00FFu;
        v ^= (v >> 16) & 0x0000FFFFu;
        xr[j] = v;
    }
    // cross-word in-thread (word = 4q+j): d=1, d=2
    xr[0] ^= xr[1]; xr[2] ^= xr[3];
    xr[0] ^= xr[2]; xr[1] ^= xr[3];
    // cross-thread: d=4 (q^1), d=8 (q^2), d=16 (q^4); stages commute per word-lane j
    #pragma unroll
    for (int j = 0; j < 4; ++j) {
        uint32_t p;
        p = __shfl_xor(xr[j], 1); if ((q & 1) == 0) xr[j] ^= p;
        p = __shfl_xor(xr[j], 2); if ((q & 2) == 0) xr[j] ^= p;
        p = __shfl_xor(xr[j], 4); if ((q & 4) == 0) xr[j] ^= p;
    }
    // park encoded words (16B-aligned, bank-balanced b128)
    *reinterpret_cast<uint4*>(&xl[r * XLP + 4 * q]) = make_uint4(xr[0], xr[1], xr[2], xr[3]);
    __syncthreads();

    // ---- Phase E: permuted expansion, coalesced float4 stores ----
    const int4 pv = reinterpret_cast<const int4*>(perm_out)[t];
    const int a0 = pv.x >> 5, s0 = pv.x & 31;
    const int a1 = pv.y >> 5, s1 = pv.y & 31;
    const int a2 = pv.z >> 5, s2 = pv.z & 31;
    const int a3 = pv.w >> 5, s3 = pv.w & 31;

    float4* outv = reinterpret_cast<float4*>(out) + (size_t)blk * (ROWS * (NPOLAR / 4)) + t;
    #pragma unroll
    for (int k = 0; k < ROWS; ++k) {
        const uint32_t* rowp = &xl[k * XLP];
        float4 o;
        o.x = (float)((rowp[a0] >> s0) & 1u);
        o.y = (float)((rowp[a1] >> s1) & 1u);
        o.z = (float)((rowp[a2] >> s2) & 1u);
        o.w = (float)((rowp[a3] >> s3) & 1u);
        outv[(size_t)k * (NPOLAR / 4)] = o;
    }
}

extern "C" void kernel_launch(void* const* d_in, const int* in_sizes, int n_in,
                              void* d_out, int out_size, void* d_ws, size_t ws_size,
                              hipStream_t stream) {
    const float* u        = (const float*)d_in[0];
    const float* crc_gen  = (const float*)d_in[1];
    const int*   info_pos = (const int*)d_in[2];
    // d_in[3] = ind_gather (butterfly structure derived analytically; unused)
    const int*   perm_out = (const int*)d_in[4];
    float* out = (float*)d_out;

    const int rows = in_sizes[0] / KT;          // 65536
    const int grid = rows / ROWS;               // 2048 blocks -> 8 blocks/CU

    polar_all_kernel<<<grid, BLOCK, 0, stream>>>(u, crc_gen, info_pos, perm_out, out);
}